// Round 3
// baseline (52.947 us; speedup 1.0000x reference)
//
#include <hip/hip_runtime.h>
#include <math.h>

#define G 128
#define NCELLS (G*G)            // 16384
#define RAD 20
#define NS 41
#define NTAPS (NS*NS)           // 1681
#define NB_FULL 1850.0f         // 1 + (2R+3)^2 entries in the mean
#define NTAIL 168.0f            // (2R+3)^2 - (2R+1)^2
#define NRULES 4
#define NQ 4
#define QROWPAD 44
#define QROWS 11
#define QSZ (QROWS*QROWPAD)     // 484 floats per-block stencil scratch
#define NBLOCKS 512
#define NSLOTS 8

// ws layout (float offsets)
#define WOFF_CNT  0                                // 8 uint slots, 64B apart (512 B, memset each launch)
#define WOFF_TAIL 128                              // 4 floats
#define WOFF_POT  132                              // 16 * NCELLS partial potentials
#define WOFF_BW   (WOFF_POT + NRULES*NQ*NCELLS)    // 512 * 484 per-block stencils

__device__ __forceinline__ float kw(float d, float irk,
                                    float rk0, float rk1, float rk2,
                                    float b0, float b1, float b2,
                                    float iw0, float iw1, float iw2) {
    float em = 1.f / (1.f + __expf((d - 1.f) * 10.f));
    float dd = d * irk;
    float u0 = (dd - rk0) * iw0;
    float u1 = (dd - rk1) * iw1;
    float u2 = (dd - rk2) * iw2;
    float ssum = b0 * __expf(-0.5f * u0 * u0)
               + b1 * __expf(-0.5f * u1 * u1)
               + b2 * __expf(-0.5f * u2 * u2);
    return em * ssum;
}

__global__ __launch_bounds__(256, 2)
void lenia_fused(const float* __restrict__ pos,
                 const float* __restrict__ x,
                 const int* __restrict__ c0v,
                 const int* __restrict__ c1v,
                 const float* __restrict__ rr,
                 const float* __restrict__ rkv,
                 const float* __restrict__ bv,
                 const float* __restrict__ wv,
                 const float* __restrict__ hv,
                 const float* __restrict__ mv,
                 const float* __restrict__ sv,
                 float* __restrict__ ws,
                 float* __restrict__ out) {
    __shared__ __align__(16) float xt[14*168];
    __shared__ float red[4];

    const int bid  = blockIdx.x;
    const int t    = threadIdx.x;
    const int q    = bid & 3;
    const int k    = (bid >> 2) & 3;
    const int tile = bid >> 4;                   // 0..31
    const int i0   = tile * 4;
    const int si0  = (q == 0) ? 0 : (q * 10 + 1);   // quarters: 11,10,10,10 rows
    const int nsi  = (q == 0) ? 11 : 10;
    const int r0   = i0 - RAD + si0;
    const int NR   = nsi + 3;
    const int ck   = c0v[k];                     // wave-uniform

    // ---- pos pass-through (independent; blocks 64..127) ----
    if (bid >= 64 && bid < 128) {
        int n = (bid - 64) * 256 + t;
        *(float2*)&out[2*n] = *(const float2*)&pos[2*n];
    }

    // ---- stage halo'd channel tile straight from interleaved x ----
    for (int idx = t; idx < NR * 168; idx += 256) {
        int rrow = idx / 168;
        int cc   = idx - rrow * 168;
        int grow = (r0 + rrow) & (G - 1);
        int gcol = (cc - 20) & (G - 1);
        xt[rrow*168 + cc] = x[grow*(G*3) + gcol*3 + ck];
    }

    // ---- per-block stencil quarter (redundant but parallel) ----
    const float irk = 1.f / rr[k];
    const float rk0 = rkv[k*3+0], rk1 = rkv[k*3+1], rk2 = rkv[k*3+2];
    const float b0  = bv[k*3+0],  b1  = bv[k*3+1],  b2  = bv[k*3+2];
    const float iw0 = 1.f / wv[k*3+0], iw1 = 1.f / wv[k*3+1], iw2 = 1.f / wv[k*3+2];
    const float invR = 1.f / (float)RAD;

    float vals[7];
    float lsum = 0.f;
    #pragma unroll
    for (int j = 0; j < 7; ++j) {
        int sidx = t + j * 256;
        float wk = 0.f;
        if (sidx < NTAPS) {
            int si = sidx / NS - RAD;
            int sj = sidx % NS - RAD;
            float d = sqrtf((float)(si*si + sj*sj)) * invR;
            wk = kw(d, irk, rk0, rk1, rk2, b0, b1, b2, iw0, iw1, iw2);
        }
        vals[j] = wk;
        lsum += wk;
    }
    // wave reduce then cross-wave via LDS
    #pragma unroll
    for (int mm = 32; mm > 0; mm >>= 1) lsum += __shfl_xor(lsum, mm, 64);
    if ((t & 63) == 0) red[t >> 6] = lsum;
    __syncthreads();                              // red ready AND xt staged
    const float S4 = red[0] + red[1] + red[2] + red[3];
    const float wself = kw(0.f, irk, rk0, rk1, rk2, b0, b1, b2, iw0, iw1, iw2);
    const float dtail = sqrtf(8192.f) * invR;
    const float wtail = kw(dtail, irk, rk0, rk1, rk2, b0, b1, b2, iw0, iw1, iw2);
    const float S = S4 + wself + NTAIL * wtail;
    const float inv = 1.f / (S * NB_FULL);

    // write this block's quarter stencil to private global scratch
    float* bw = ws + WOFF_BW + bid * QSZ;
    const int lo = si0 * NS, hi = (si0 + nsi) * NS;
    #pragma unroll
    for (int j = 0; j < 7; ++j) {
        int sidx = t + j * 256;
        if (sidx >= lo && sidx < hi) {
            float v = vals[j] * inv;
            if (sidx == RAD*NS + RAD) v += wself * inv;   // fold self slot into (0,0)
            int l = sidx - lo;
            bw[(l / NS) * QROWPAD + (l % NS)] = v;
        }
    }
    if (t < QROWS * 3) bw[(t / 3) * QROWPAD + NS + (t % 3)] = 0.f;   // zero pad cols
    if (tile == 0 && q == 0 && t == 0) ws[WOFF_TAIL + k] = NTAIL * wtail * inv;
    __syncthreads();                              // drains vmcnt: scratch visible block-wide

    // ---- conv: 4 rows x 128 cols, 2 adjacent cells per thread ----
    const int row = t >> 6;
    const int colbase = (t & 63) * 2;
    float a0 = 0.f, a1 = 0.f, a2 = 0.f, a3 = 0.f;

    for (int ii = 0; ii < nsi; ++ii) {
        const float* rp = &xt[(row + ii)*168 + colbase];
        float wwin[42];
        #pragma unroll
        for (int u = 0; u < 21; ++u) {
            float2 v = *(const float2*)&rp[2*u];
            wwin[2*u] = v.x; wwin[2*u+1] = v.y;
        }
        const float* wr = bw + ii * QROWPAD;     // block-uniform, L1-hot
        float wrow[44];
        #pragma unroll
        for (int u = 0; u < 11; ++u) {
            float4 v = *(const float4*)&wr[4*u];
            wrow[4*u] = v.x; wrow[4*u+1] = v.y; wrow[4*u+2] = v.z; wrow[4*u+3] = v.w;
        }
        #pragma unroll
        for (int s2 = 0; s2 < 40; s2 += 2) {
            a0 = fmaf(wrow[s2],   wwin[s2],   a0);
            a1 = fmaf(wrow[s2],   wwin[s2+1], a1);
            a2 = fmaf(wrow[s2+1], wwin[s2+1], a2);
            a3 = fmaf(wrow[s2+1], wwin[s2+2], a3);
        }
        a0 = fmaf(wrow[40], wwin[40], a0);
        a1 = fmaf(wrow[40], wwin[41], a1);
    }

    int cell = (i0 + row) * G + colbase;
    float* pp = ws + WOFF_POT + (k * NQ + q) * NCELLS;
    pp[cell]     = a0 + a2;
    pp[cell + 1] = a1 + a3;

    // ---- global barrier: arrive (all blocks), spin (blocks 0..63 only) ----
    __syncthreads();                              // all stores of this block issued+drained
    unsigned int* cnt = (unsigned int*)ws;        // 8 slots, 64B apart
    if (t == 0) {
        __threadfence();                          // release: make pot/tail stores device-visible
        __hip_atomic_fetch_add(&cnt[(bid & 7) * 16], 1u,
                               __ATOMIC_ACQ_REL, __HIP_MEMORY_SCOPE_AGENT);
    }
    if (bid >= 64) return;

    if (t == 0) {
        unsigned int ssum;
        do {
            __builtin_amdgcn_s_sleep(2);
            ssum = 0;
            #pragma unroll
            for (int i = 0; i < NSLOTS; ++i)
                ssum += __hip_atomic_load(&cnt[i * 16], __ATOMIC_ACQUIRE,
                                          __HIP_MEMORY_SCOPE_AGENT);
        } while (ssum < NBLOCKS);
        __threadfence();                          // acquire: invalidate stale cached lines
    }
    __syncthreads();

    // ---- update: 256 cells per block ----
    {
        int n = bid * 256 + t;
        float xv0 = x[n*3 + 0], xv1 = x[n*3 + 1], xv2 = x[n*3 + 2];
        float d0 = 0.f, d1 = 0.f, d2 = 0.f;
        #pragma unroll
        for (int kk = 0; kk < NRULES; ++kk) {
            float pot = ws[WOFF_TAIL + kk] * x[c0v[kk]];   // tail slots: cell 0
            #pragma unroll
            for (int qq = 0; qq < NQ; ++qq)
                pot += ws[WOFF_POT + (kk * NQ + qq) * NCELLS + n];
            float u = pot - mv[kk];
            float sk = sv[kk];
            float field = __expf(-u*u / (2.f * sk * sk) - 0.001f) * 2.f - 1.f;
            float add = hv[kk] * field;
            int c = c1v[kk];
            if (c == 0) d0 += add; else if (c == 1) d1 += add; else d2 += add;
        }
        float* ox = out + 2 * NCELLS;
        ox[n*3 + 0] = fminf(fmaxf(xv0 + d0 * 0.1f, 0.f), 1.f);
        ox[n*3 + 1] = fminf(fmaxf(xv1 + d1 * 0.1f, 0.f), 1.f);
        ox[n*3 + 2] = fminf(fmaxf(xv2 + d2 * 0.1f, 0.f), 1.f);
    }
}

extern "C" void kernel_launch(void* const* d_in, const int* in_sizes, int n_in,
                              void* d_out, int out_size, void* d_ws, size_t ws_size,
                              hipStream_t stream) {
    const float* pos = (const float*)d_in[0];
    const float* x   = (const float*)d_in[1];
    const int*   c0  = (const int*)  d_in[2];
    const int*   c1  = (const int*)  d_in[3];
    const float* r   = (const float*)d_in[4];
    const float* rk  = (const float*)d_in[5];
    const float* b   = (const float*)d_in[6];
    const float* w   = (const float*)d_in[7];
    const float* h   = (const float*)d_in[8];
    const float* m   = (const float*)d_in[9];
    const float* s   = (const float*)d_in[10];
    float* out = (float*)d_out;
    float* ws  = (float*)d_ws;

    // zero the 8 barrier slots (poison-proof; capturable as a memset node)
    hipMemsetAsync(ws, 0, 512, stream);
    lenia_fused<<<NBLOCKS, 256, 0, stream>>>(pos, x, c0, c1, r, rk, b, w, h, m, s, ws, out);
}

// Round 4
// 22.751 us; speedup vs baseline: 2.3273x; 2.3273x over previous
//
#include <hip/hip_runtime.h>
#include <math.h>

#define G 128
#define NCELLS (G*G)            // 16384
#define RAD 20
#define NS 41
#define NTAPS (NS*NS)           // 1681
#define NB_FULL 1850.0f         // 1 + (2R+3)^2 entries in the mean
#define NTAIL 168.0f            // (2R+3)^2 - (2R+1)^2
#define NRULES 4
#define NQ 4
#define QROWPAD 44
#define QROWS 11
#define QSZ (QROWS*QROWPAD)     // 484 floats per-block stencil scratch
#define CONV_BLOCKS 256         // 16 tiles x 4 rules x 4 quarters

// ws layout (float offsets)
#define WOFF_TAIL 0                                // 4 floats
#define WOFF_POT  16                               // 16 * NCELLS partial potentials
#define WOFF_BW   (WOFF_POT + NRULES*NQ*NCELLS)    // 256 * 484 per-block stencils

__device__ __forceinline__ float kw(float d, float irk,
                                    float rk0, float rk1, float rk2,
                                    float b0, float b1, float b2,
                                    float iw0, float iw1, float iw2) {
    float em = 1.f / (1.f + __expf((d - 1.f) * 10.f));
    float dd = d * irk;
    float u0 = (dd - rk0) * iw0;
    float u1 = (dd - rk1) * iw1;
    float u2 = (dd - rk2) * iw2;
    return em * (b0 * __expf(-0.5f * u0 * u0)
               + b1 * __expf(-0.5f * u1 * u1)
               + b2 * __expf(-0.5f * u2 * u2));
}

// 256 blocks: (16 eight-row tiles) x (4 rules) x (4 stencil-row quarters).
// 256 threads = 8 rows x 32 lanes; each thread computes 4 adjacent cells.
__global__ __launch_bounds__(256)
void lenia_conv(const float* __restrict__ x,
                const int* __restrict__ c0v,
                const float* __restrict__ rr,
                const float* __restrict__ rkv,
                const float* __restrict__ bv,
                const float* __restrict__ wv,
                float* __restrict__ ws) {
    __shared__ __align__(16) float xt[18*168];   // up to 18 halo'd rows
    __shared__ float red[4];

    const int bid  = blockIdx.x;
    const int q    = bid & 3;
    const int k    = (bid >> 2) & 3;
    const int tile = bid >> 4;                   // 0..15
    const int i0   = tile * 8;
    const int t    = threadIdx.x;
    const int si0  = (q == 0) ? 0 : (q * 10 + 1);   // quarters: 11,10,10,10 rows
    const int nsi  = (q == 0) ? 11 : 10;
    const int r0   = i0 - RAD + si0;
    const int NR   = nsi + 7;                    // <= 18 staged rows
    const int ck   = c0v[k];                     // wave-uniform

    // ---- stage halo'd channel tile straight from interleaved x ----
    for (int idx = t; idx < NR * 168; idx += 256) {
        int rrow = idx / 168;
        int cc   = idx - rrow * 168;
        int grow = (r0 + rrow) & (G - 1);
        int gcol = (cc - 20) & (G - 1);
        xt[rrow*168 + cc] = x[grow*(G*3) + gcol*3 + ck];
    }

    // ---- per-block stencil quarter (redundant but parallel; proven in R3) ----
    const float irk = 1.f / rr[k];
    const float rk0 = rkv[k*3+0], rk1 = rkv[k*3+1], rk2 = rkv[k*3+2];
    const float b0  = bv[k*3+0],  b1  = bv[k*3+1],  b2  = bv[k*3+2];
    const float iw0 = 1.f / wv[k*3+0], iw1 = 1.f / wv[k*3+1], iw2 = 1.f / wv[k*3+2];
    const float invR = 1.f / (float)RAD;

    float vals[7];
    float lsum = 0.f;
    #pragma unroll
    for (int j = 0; j < 7; ++j) {
        int sidx = t + j * 256;
        float wk = 0.f;
        if (sidx < NTAPS) {
            int si = sidx / NS - RAD;
            int sj = sidx % NS - RAD;
            float d = sqrtf((float)(si*si + sj*sj)) * invR;
            wk = kw(d, irk, rk0, rk1, rk2, b0, b1, b2, iw0, iw1, iw2);
        }
        vals[j] = wk;
        lsum += wk;
    }
    #pragma unroll
    for (int mm = 32; mm > 0; mm >>= 1) lsum += __shfl_xor(lsum, mm, 64);
    if ((t & 63) == 0) red[t >> 6] = lsum;
    __syncthreads();                              // red ready AND xt staged
    const float S4 = red[0] + red[1] + red[2] + red[3];
    const float wself = kw(0.f, irk, rk0, rk1, rk2, b0, b1, b2, iw0, iw1, iw2);
    const float dtail = sqrtf(8192.f) * invR;
    const float wtail = kw(dtail, irk, rk0, rk1, rk2, b0, b1, b2, iw0, iw1, iw2);
    const float S = S4 + wself + NTAIL * wtail;
    const float inv = 1.f / (S * NB_FULL);

    // write this block's quarter stencil to private global scratch (SMEM path on readback)
    float* bw = ws + WOFF_BW + bid * QSZ;
    const int lo = si0 * NS, hi = (si0 + nsi) * NS;
    #pragma unroll
    for (int j = 0; j < 7; ++j) {
        int sidx = t + j * 256;
        if (sidx >= lo && sidx < hi) {
            float v = vals[j] * inv;
            if (sidx == RAD*NS + RAD) v += wself * inv;   // fold self slot into (0,0)
            int l = sidx - lo;
            bw[(l / NS) * QROWPAD + (l % NS)] = v;
        }
    }
    if (t < QROWS * 3) bw[(t / 3) * QROWPAD + NS + (t % 3)] = 0.f;   // zero pad cols
    if (tile == 0 && q == 0 && t == 0) ws[WOFF_TAIL + k] = NTAIL * wtail * inv;
    __syncthreads();                              // drains vmcnt: bw visible block-wide

    // ---- conv: 8 rows x 32 lanes, 4 adjacent cells per thread ----
    const int row = t >> 5;
    const int cb  = (t & 31) * 4;
    float a0 = 0.f, a1 = 0.f, a2 = 0.f, a3 = 0.f;

    for (int ii = 0; ii < nsi; ++ii) {
        const float* rp = &xt[(row + ii)*168 + cb];   // 16B-aligned
        float wwin[44];
        #pragma unroll
        for (int u = 0; u < 11; ++u) {
            float4 v = *(const float4*)&rp[4*u];
            wwin[4*u] = v.x; wwin[4*u+1] = v.y; wwin[4*u+2] = v.z; wwin[4*u+3] = v.w;
        }
        const float* wr = bw + ii * QROWPAD;          // wave-uniform address
        float wrow[44];
        #pragma unroll
        for (int u = 0; u < 11; ++u) {
            float4 v = *(const float4*)&wr[4*u];
            wrow[4*u] = v.x; wrow[4*u+1] = v.y; wrow[4*u+2] = v.z; wrow[4*u+3] = v.w;
        }
        #pragma unroll
        for (int s2 = 0; s2 < 41; ++s2) {
            a0 = fmaf(wrow[s2], wwin[s2],   a0);
            a1 = fmaf(wrow[s2], wwin[s2+1], a1);
            a2 = fmaf(wrow[s2], wwin[s2+2], a2);
            a3 = fmaf(wrow[s2], wwin[s2+3], a3);
        }
    }

    int cell = (i0 + row) * G + cb;
    float4 res; res.x = a0; res.y = a1; res.z = a2; res.w = a3;
    *(float4*)&ws[WOFF_POT + (k * NQ + q) * NCELLS + cell] = res;
}

// 64 blocks x 256: sum partials, growth, delta, clip, plus pos pass-through.
__global__ __launch_bounds__(256)
void lenia_update(const float* __restrict__ pos,
                  const float* __restrict__ x,
                  const int* __restrict__ c0v,
                  const int* __restrict__ c1v,
                  const float* __restrict__ hv,
                  const float* __restrict__ mv,
                  const float* __restrict__ sv,
                  const float* __restrict__ ws,
                  float* __restrict__ out) {
    int n = blockIdx.x * 256 + threadIdx.x;
    *(float2*)&out[2*n] = *(const float2*)&pos[2*n];

    float xv0 = x[n*3 + 0], xv1 = x[n*3 + 1], xv2 = x[n*3 + 2];
    float d0 = 0.f, d1 = 0.f, d2 = 0.f;
    #pragma unroll
    for (int kk = 0; kk < NRULES; ++kk) {
        float pot = ws[WOFF_TAIL + kk] * x[c0v[kk]];   // tail slots all index cell 0
        #pragma unroll
        for (int qq = 0; qq < NQ; ++qq)
            pot += ws[WOFF_POT + (kk * NQ + qq) * NCELLS + n];
        float u = pot - mv[kk];
        float sk = sv[kk];
        float field = __expf(-u*u / (2.f * sk * sk) - 0.001f) * 2.f - 1.f;
        float add = hv[kk] * field;
        int c = c1v[kk];   // wave-uniform
        if (c == 0) d0 += add; else if (c == 1) d1 += add; else d2 += add;
    }
    float* ox = out + 2 * NCELLS;
    ox[n*3 + 0] = fminf(fmaxf(xv0 + d0 * 0.1f, 0.f), 1.f);
    ox[n*3 + 1] = fminf(fmaxf(xv1 + d1 * 0.1f, 0.f), 1.f);
    ox[n*3 + 2] = fminf(fmaxf(xv2 + d2 * 0.1f, 0.f), 1.f);
}

extern "C" void kernel_launch(void* const* d_in, const int* in_sizes, int n_in,
                              void* d_out, int out_size, void* d_ws, size_t ws_size,
                              hipStream_t stream) {
    const float* pos = (const float*)d_in[0];
    const float* x   = (const float*)d_in[1];
    const int*   c0  = (const int*)  d_in[2];
    const int*   c1  = (const int*)  d_in[3];
    const float* r   = (const float*)d_in[4];
    const float* rk  = (const float*)d_in[5];
    const float* b   = (const float*)d_in[6];
    const float* w   = (const float*)d_in[7];
    const float* h   = (const float*)d_in[8];
    const float* m   = (const float*)d_in[9];
    const float* s   = (const float*)d_in[10];
    float* out = (float*)d_out;
    float* ws  = (float*)d_ws;

    lenia_conv<<<CONV_BLOCKS, 256, 0, stream>>>(x, c0, r, rk, b, w, ws);
    lenia_update<<<NCELLS/256, 256, 0, stream>>>(pos, x, c0, c1, h, m, s, ws, out);
}